// Round 1
// baseline (619.974 us; speedup 1.0000x reference)
//
#include <hip/hip_runtime.h>
#include <math.h>

#define LATENT   1024
#define WORD     64
#define NB_WORD  8192
#define BATCH    2048
#define NROWS    (BATCH * LATENT / WORD)   // 32768
#define NELEM    (BATCH * LATENT)          // 2097152
#define MSPLITS  8
#define MCHUNK   (NB_WORD / MSPLITS)       // 1024

// ---------------- kernel 1: e2[m] = sum_k emb[m][k]^2 ----------------
__global__ __launch_bounds__(256) void vq_e2_kernel(
    const float* __restrict__ emb, float* __restrict__ e2) {
    int m = blockIdx.x * 256 + threadIdx.x;
    if (m >= NB_WORD) return;
    const float4* ep = reinterpret_cast<const float4*>(emb + (size_t)m * WORD);
    float s0 = 0.f, s1 = 0.f, s2 = 0.f, s3 = 0.f;
#pragma unroll
    for (int i = 0; i < 16; ++i) {
        float4 v = ep[i];
        s0 = fmaf(v.x, v.x, s0);
        s1 = fmaf(v.y, v.y, s1);
        s2 = fmaf(v.z, v.z, s2);
        s3 = fmaf(v.w, v.w, s3);
    }
    e2[m] = (s0 + s1) + (s2 + s3);
}

// ---------------- kernel 2: per-row argmin over a codeword chunk ------
// One row per lane, row in VGPRs; codeword is wave-uniform -> scalar loads.
__global__ __launch_bounds__(256) void vq_argmin_kernel(
    const float* __restrict__ z, const float* __restrict__ emb,
    const float* __restrict__ e2, unsigned long long* __restrict__ best) {
    const int row = blockIdx.x * 256 + threadIdx.x;
    const int m0  = blockIdx.y * MCHUNK;

    // load this lane's row into registers
    float zr[WORD];
    const float4* zp = reinterpret_cast<const float4*>(z + (size_t)row * WORD);
#pragma unroll
    for (int i = 0; i < 16; ++i) {
        float4 v = zp[i];
        zr[4*i+0] = v.x; zr[4*i+1] = v.y; zr[4*i+2] = v.z; zr[4*i+3] = v.w;
    }
    float z2 = 0.f;
#pragma unroll
    for (int k = 0; k < WORD; ++k) z2 = fmaf(zr[k], zr[k], z2);

    float bestd = INFINITY;
    int   bestm = m0;

    for (int m = m0; m < m0 + MCHUNK; ++m) {
        const float4* ep = reinterpret_cast<const float4*>(emb + (size_t)m * WORD);
        float a0 = 0.f, a1 = 0.f, a2 = 0.f, a3 = 0.f;
#pragma unroll
        for (int i = 0; i < 16; ++i) {
            float4 ev = ep[i];   // wave-uniform -> s_load
            a0 = fmaf(zr[4*i+0], ev.x, a0);
            a1 = fmaf(zr[4*i+1], ev.y, a1);
            a2 = fmaf(zr[4*i+2], ev.z, a2);
            a3 = fmaf(zr[4*i+3], ev.w, a3);
        }
        float acc = (a0 + a1) + (a2 + a3);
        // reference order: (z2 + e2[m]) - 2*dot ; 2*acc exact -> fma == sub
        float d = fmaf(-2.0f, acc, z2 + e2[m]);
        bestm = (d < bestd) ? m : bestm;
        bestd = fminf(d, bestd);
    }

    // pack (ordered float bits, idx) so atomicMin picks min-dist, tie -> min idx
    unsigned int db = __float_as_uint(bestd);
    db = (db & 0x80000000u) ? ~db : (db | 0x80000000u);
    unsigned long long key = ((unsigned long long)db << 32) | (unsigned int)bestm;
    atomicMin(best + row, key);
}

// ---------------- kernel 3: gather + straight-through output + loss ---
__global__ __launch_bounds__(256) void vq_out_kernel(
    const float* __restrict__ z, const float* __restrict__ emb,
    const unsigned long long* __restrict__ best,
    float* __restrict__ out, float* __restrict__ lsum) {
    const int base = (blockIdx.x * 256 + threadIdx.x) * 8;   // 8 elems/thread
    const int row  = base >> 6;                              // 8 | 64, row fixed
    const int m    = (int)(best[row] & 0xFFFFFFFFull);

    const float4* zp = reinterpret_cast<const float4*>(z + base);
    const float4* qp = reinterpret_cast<const float4*>(emb + (size_t)m * WORD + (base & 63));
    float4* op = reinterpret_cast<float4*>(out + base);

    float s = 0.f;
#pragma unroll
    for (int i = 0; i < 2; ++i) {
        float4 zv = zp[i];
        float4 qv = qp[i];
        float dx = qv.x - zv.x, dy = qv.y - zv.y, dz = qv.z - zv.z, dw = qv.w - zv.w;
        float4 ov;
        ov.x = zv.x + dx; ov.y = zv.y + dy; ov.z = zv.z + dz; ov.w = zv.w + dw;
        op[i] = ov;
        s += dx*dx + dy*dy + dz*dz + dw*dw;
    }

    // wave reduce
#pragma unroll
    for (int off = 32; off > 0; off >>= 1) s += __shfl_down(s, off);
    __shared__ float wsum[4];
    int lane = threadIdx.x & 63, wid = threadIdx.x >> 6;
    if (lane == 0) wsum[wid] = s;
    __syncthreads();
    if (threadIdx.x == 0)
        atomicAdd(lsum, (wsum[0] + wsum[1]) + (wsum[2] + wsum[3]));
}

// ---------------- kernel 4: finalize loss -----------------------------
__global__ void vq_loss_kernel(const float* __restrict__ lsum,
                               float* __restrict__ loss_out) {
    float mean = lsum[0] * (1.0f / (float)NELEM);   // /2^21 exact
    loss_out[0] = mean + 2.5f * mean;
}

extern "C" void kernel_launch(void* const* d_in, const int* in_sizes, int n_in,
                              void* d_out, int out_size, void* d_ws, size_t ws_size,
                              hipStream_t stream) {
    const float* z   = (const float*)d_in[0];   // z_mean (2048,1024)
    // d_in[1] = z_log_var, unused by the reference
    const float* emb = (const float*)d_in[2];   // (8192,64)
    float* out = (float*)d_out;                 // [z_q_st flat (2097152), loss]

    // ws layout: e2 (8192 f32) | best (32768 u64) | lsum (1 f32)
    float* e2 = (float*)d_ws;
    unsigned long long* best =
        (unsigned long long*)((char*)d_ws + NB_WORD * sizeof(float));
    float* lsum = (float*)((char*)best + NROWS * sizeof(unsigned long long));

    hipMemsetAsync(best, 0xFF, NROWS * sizeof(unsigned long long), stream);
    hipMemsetAsync(lsum, 0, sizeof(float), stream);

    vq_e2_kernel<<<NB_WORD / 256, 256, 0, stream>>>(emb, e2);
    vq_argmin_kernel<<<dim3(NROWS / 256, MSPLITS), 256, 0, stream>>>(z, emb, e2, best);
    vq_out_kernel<<<NELEM / (256 * 8), 256, 0, stream>>>(z, emb, best, out, lsum);
    vq_loss_kernel<<<1, 1, 0, stream>>>(lsum, out + NELEM);
}